// Round 4
// baseline (407.097 us; speedup 1.0000x reference)
//
#include <hip/hip_runtime.h>

// ---------------------------------------------------------------------------
// TurboQuantAttention — round 6 (round-5 structure, PV addressing fixed).
// attn2: keys split 2-way (grid 1024, 4 blocks/CU = 4 waves/SIMD), single-
// tile double-buffered DMA pipeline (32.8KB LDS), one raw barrier + vmcnt(0)
// per tile, stage-ahead-1. Static softmax bound -> key-half partials sum
// exactly: attn2 writes unnormalized acc (half A -> kr, half B -> d_out as
// scratch) + partial lsums; rot_oc combines (accA+accB)/(lA+lB) and applies
// the inverse rotation.
// BUGFIX vs round 5: V LDS read offsets are u64-unit based; the 16B unit
// (half,hi,d) lives at u64 index 2*((2*half+hi)*128 + dt*32 + r31), so
// vbse = hi*256 + 2*r31, pa at vb+dt*64, pb at vb+512+dt*64.
// ---------------------------------------------------------------------------

typedef float    f32x4  __attribute__((ext_vector_type(4)));
typedef float    f32x16 __attribute__((ext_vector_type(16)));
typedef __bf16   bf16x8 __attribute__((ext_vector_type(8)));
typedef __bf16   bf16x4 __attribute__((ext_vector_type(4)));
typedef _Float16 f16x8  __attribute__((ext_vector_type(8)));
typedef unsigned long long u64;

#define SLEN 2048
#define DH   128

static __device__ __forceinline__ f32x16 zero16() {
  f32x16 z;
#pragma unroll
  for (int i = 0; i < 16; ++i) z[i] = 0.f;
  return z;
}

static __device__ __forceinline__ f32x16 mfma_bf16_32x32x16(bf16x8 a, bf16x8 b, f32x16 c) {
  return __builtin_amdgcn_mfma_f32_32x32x16_bf16(a, b, c, 0, 0, 0);
}
static __device__ __forceinline__ f32x16 mfma_f16_32x32x16(f16x8 a, f16x8 b, f32x16 c) {
  return __builtin_amdgcn_mfma_f32_32x32x16_f16(a, b, c, 0, 0, 0);
}

// async global->LDS, 16B per lane; lds base is wave-uniform, lane i lands at +i*16
static __device__ __forceinline__ void lds_dma16(const void* g, void* l) {
  __builtin_amdgcn_global_load_lds(
      (const __attribute__((address_space(1))) void*)(unsigned long long)g,
      (__attribute__((address_space(3))) void*)(unsigned int)(unsigned long long)l,
      16, 0, 0);
}

// quantize->dequantize one element, op-order identical to reference (fp32)
static __device__ __forceinline__ float qdq(float xr, float xmax, float qs) {
  float xs = xr / xmax * 3.5f;
  float xq = rintf(xs * 4.0f) * 0.25f;
  xq = fminf(3.5f, fmaxf(-3.5f, xq));
  float res = xs - xq;
  float sg = (res > 0.0f) ? 1.0f : ((res < 0.0f) ? -1.0f : 0.0f);
  float xc = xq + sg * qs * xmax;
  return xc / 3.5f * xmax;
}

static __device__ __forceinline__ unsigned short bfbits(float f) {
  __bf16 b = (__bf16)f;
  return __builtin_bit_cast(unsigned short, b);
}

// ---------------------------------------------------------------------------
// prep_R: split R (fp32 128x128) into f16 hi/lo, row-major and transposed.
// ---------------------------------------------------------------------------
__global__ __launch_bounds__(256) void prep_R(
    const float* __restrict__ R, _Float16* __restrict__ Bhi,
    _Float16* __restrict__ Blo, _Float16* __restrict__ BhiT,
    _Float16* __restrict__ BloT)
{
  int i = blockIdx.x * 256 + threadIdx.x;   // 0..16383
  int kk = i >> 7, n = i & 127;
  float r = R[i];
  _Float16 h = (_Float16)r;
  _Float16 l = (_Float16)(r - (float)h);
  Bhi[i] = h; Blo[i] = l;
  BhiT[n * 128 + kk] = h; BloT[n * 128 + kk] = l;
}

// ---------------------------------------------------------------------------
// rot_body: C = X(65536x128) @ B^T. NT=3: f16 hi/lo 3-term; NT=1: single pass.
// MODE 0: fp32 out + per-wave absmax -> part[bid*4+wave]
// MODE 1: bf16 out scaled by log2(e)/sqrt(128) + fused row norms -> qn (q)
// ---------------------------------------------------------------------------
template<int NT, int MODE>
static __device__ __forceinline__ void rot_body(
    const float* __restrict__ X, const _Float16* __restrict__ Gh,
    const _Float16* __restrict__ Gl, void* __restrict__ OUTv,
    float* __restrict__ part, float* __restrict__ qn, int bid)
{
  __shared__ _Float16 BH[128 * 128];
  __shared__ _Float16 BL[(NT == 3) ? 128 * 128 : 8];

  const int tid = threadIdx.x, wave = tid >> 6, lane = tid & 63;
  const int r31 = lane & 31, hi = lane >> 5;
  const long r0 = (long)bid * 128;

  // stage B via DMA, XOR-swizzled at 16B-chunk granularity
#pragma unroll
  for (int u = 0; u < 8; ++u) {
    int c = (wave * 8 + u) * 64 + lane;
    int n = c >> 4, p = c & 15, ch = p ^ (n & 7);
    lds_dma16(Gh + n * 128 + ch * 8, BH + (wave * 8 + u) * 512);
    if constexpr (NT == 3)
      lds_dma16(Gl + n * 128 + ch * 8, BL + (wave * 8 + u) * 512);
  }

  // A: load X rows direct from global, split f16 hi/lo in regs
  const long rowg = r0 + wave * 32 + r31;
  f16x8 ah[8], al[8];
#pragma unroll
  for (int t = 0; t < 8; ++t) {
    f32x4 x0 = *(const f32x4*)&X[rowg * 128 + t * 16 + hi * 8];
    f32x4 x1 = *(const f32x4*)&X[rowg * 128 + t * 16 + hi * 8 + 4];
#pragma unroll
    for (int j = 0; j < 4; ++j) {
      _Float16 h0 = (_Float16)x0[j]; ah[t][j] = h0;
      _Float16 h1 = (_Float16)x1[j]; ah[t][4 + j] = h1;
      if constexpr (NT == 3) {
        al[t][j]     = (_Float16)(x0[j] - (float)h0);
        al[t][4 + j] = (_Float16)(x1[j] - (float)h1);
      }
    }
  }
  __syncthreads();

  f32x16 acc[4];
#pragma unroll
  for (int ct = 0; ct < 4; ++ct) acc[ct] = zero16();

#pragma unroll
  for (int ct = 0; ct < 4; ++ct) {
#pragma unroll
    for (int t = 0; t < 8; ++t) {
      int idx = (ct * 32 + r31) * 128 + (((2 * t + hi) ^ (r31 & 7)) * 8);
      f16x8 bh = *(const f16x8*)&BH[idx];
      acc[ct] = mfma_f16_32x32x16(ah[t], bh, acc[ct]);
      if constexpr (NT == 3) {
        f16x8 bl = *(const f16x8*)&BL[idx];
        acc[ct] = mfma_f16_32x32x16(ah[t], bl, acc[ct]);
        acc[ct] = mfma_f16_32x32x16(al[t], bh, acc[ct]);
      }
    }
  }

  if constexpr (MODE == 0) {
    float* OUT = (float*)OUTv;
    float am = 0.f;
#pragma unroll
    for (int ct = 0; ct < 4; ++ct)
#pragma unroll
      for (int r = 0; r < 16; ++r) {
        long grow = r0 + wave * 32 + (r & 3) + 8 * (r >> 2) + 4 * hi;
        float v = acc[ct][r];
        OUT[grow * 128 + ct * 32 + r31] = v;
        am = fmaxf(am, fabsf(v));
      }
#pragma unroll
    for (int m = 1; m <= 32; m <<= 1) am = fmaxf(am, __shfl_xor(am, m, 64));
    if (lane == 0) part[bid * 4 + wave] = am;
  } else if constexpr (MODE == 1) {
    __bf16* OUT = (__bf16*)OUTv;
    const float sc = 0.12751743342f;   // log2(e)/sqrt(128): exp2-domain scores
    float rs[16];
#pragma unroll
    for (int r = 0; r < 16; ++r) rs[r] = 0.f;
#pragma unroll
    for (int ct = 0; ct < 4; ++ct)
#pragma unroll
      for (int r = 0; r < 16; ++r) {
        long grow = r0 + wave * 32 + (r & 3) + 8 * (r >> 2) + 4 * hi;
        __bf16 b = (__bf16)(acc[ct][r] * sc);
        OUT[grow * 128 + ct * 32 + r31] = b;
        float fb = (float)b;
        rs[r] += fb * fb;
      }
    // row sumsq: reduce across the 32 lanes of this hi-half, then one lane writes
#pragma unroll
    for (int r = 0; r < 16; ++r) {
#pragma unroll
      for (int msk = 1; msk <= 16; msk <<= 1) rs[r] += __shfl_xor(rs[r], msk, 64);
      if (r31 == r)
        qn[r0 + wave * 32 + (r & 3) + 8 * (r >> 2) + 4 * hi] = sqrtf(rs[r]);
    }
  }
}

// merged k+v rotation: blocks 0..511 -> k, 512..1023 -> v
__global__ __launch_bounds__(256) void rot_kv_kernel(
    const float* __restrict__ K, const float* __restrict__ V,
    const _Float16* __restrict__ Gh, const _Float16* __restrict__ Gl,
    float* __restrict__ kr, float* __restrict__ vr,
    float* __restrict__ kpart, float* __restrict__ vpart)
{
  const bool isv = blockIdx.x >= 512;
  rot_body<3, 0>(isv ? V : K, Gh, Gl, isv ? (void*)vr : (void*)kr,
                 isv ? vpart : kpart, nullptr, blockIdx.x & 511);
}

__global__ __launch_bounds__(256) void rot_q_kernel(
    const float* __restrict__ X, const _Float16* __restrict__ Gh,
    const _Float16* __restrict__ Gl, __bf16* __restrict__ qb,
    float* __restrict__ qn)
{
  rot_body<1, 1>(X, Gh, Gl, (void*)qb, nullptr, qn, blockIdx.x);
}

// ---------------------------------------------------------------------------
// rot_oc: combine key-half partials + inverse rotation.
//   x = (pA + pB) * (1/(lA+lB)), then y = x @ R (Bhi row-major, NT=1).
//   pB aliases d_out: each block reads rows [r0,r0+128) before writing the
//   same rows (reads complete before the __syncthreads; rows block-disjoint).
// ---------------------------------------------------------------------------
__global__ __launch_bounds__(256) void rot_oc_kernel(
    const float* __restrict__ pA, const float* __restrict__ pB,
    const float* __restrict__ lsumP, const _Float16* __restrict__ Gh,
    float* __restrict__ OUT)
{
  __shared__ _Float16 BH[128 * 128];

  const int tid = threadIdx.x, wave = tid >> 6, lane = tid & 63;
  const int r31 = lane & 31, hi = lane >> 5;
  const long r0 = (long)blockIdx.x * 128;

#pragma unroll
  for (int u = 0; u < 8; ++u) {
    int c = (wave * 8 + u) * 64 + lane;
    int n = c >> 4, p = c & 15, ch = p ^ (n & 7);
    lds_dma16(Gh + n * 128 + ch * 8, BH + (wave * 8 + u) * 512);
  }

  const long rowg = r0 + wave * 32 + r31;
  const float rinv = 1.0f / (lsumP[rowg] + lsumP[65536 + rowg]);
  f16x8 ah[8];
#pragma unroll
  for (int t = 0; t < 8; ++t) {
    f32x4 a0 = *(const f32x4*)&pA[rowg * 128 + t * 16 + hi * 8];
    f32x4 a1 = *(const f32x4*)&pA[rowg * 128 + t * 16 + hi * 8 + 4];
    f32x4 b0 = *(const f32x4*)&pB[rowg * 128 + t * 16 + hi * 8];
    f32x4 b1 = *(const f32x4*)&pB[rowg * 128 + t * 16 + hi * 8 + 4];
#pragma unroll
    for (int j = 0; j < 4; ++j) {
      ah[t][j]     = (_Float16)((a0[j] + b0[j]) * rinv);
      ah[t][4 + j] = (_Float16)((a1[j] + b1[j]) * rinv);
    }
  }
  __syncthreads();

  f32x16 acc[4];
#pragma unroll
  for (int ct = 0; ct < 4; ++ct) acc[ct] = zero16();
#pragma unroll
  for (int ct = 0; ct < 4; ++ct) {
#pragma unroll
    for (int t = 0; t < 8; ++t) {
      int idx = (ct * 32 + r31) * 128 + (((2 * t + hi) ^ (r31 & 7)) * 8);
      f16x8 bh = *(const f16x8*)&BH[idx];
      acc[ct] = mfma_f16_32x32x16(ah[t], bh, acc[ct]);
    }
  }
#pragma unroll
  for (int ct = 0; ct < 4; ++ct)
#pragma unroll
    for (int r = 0; r < 16; ++r) {
      long grow = r0 + wave * 32 + (r & 3) + 8 * (r >> 2) + 4 * hi;
      OUT[grow * 128 + ct * 32 + r31] = acc[ct][r];
    }
}

// ---------------------------------------------------------------------------
// quantize+dequant v -> per-tile x16 B-fragment layout:
//   per 32-key tile (8KB): 16B unit u = (half*2+hi)*128 + d holds keys
//   {16*half+4*hi+(0..3), 16*half+4*hi+8+(0..3)} at row d.
// ---------------------------------------------------------------------------
__global__ __launch_bounds__(256) void quantize_vt_kernel(
    const float* __restrict__ vr, const float* __restrict__ vpart,
    const float* __restrict__ qjl, u64* __restrict__ vdt2)
{
  __shared__ unsigned int Ts32[128][18];
  __shared__ float sm[4];
  const int tid = threadIdx.x;

  float m = 0.f;
  for (int i = tid; i < 2048; i += 256) m = fmaxf(m, vpart[i]);
#pragma unroll
  for (int msk = 1; msk <= 32; msk <<= 1) m = fmaxf(m, __shfl_xor(m, msk, 64));
  if ((tid & 63) == 0) sm[tid >> 6] = m;
  __syncthreads();
  const float xmax = fmaxf(fmaxf(sm[0], sm[1]), fmaxf(sm[2], sm[3])) + 1e-8f;
  const float qs = qjl[0];

  const int bh = blockIdx.x >> 6, blk = blockIdx.x & 63;
  const int s0 = blk * 32;
  const int sp  = tid & 15;
  const int dch = tid >> 4;
  const long rb = (long)bh * SLEN + s0;
  const float* p0 = &vr[(rb + sp * 2    ) * 128 + dch * 8];
  const float* p1 = &vr[(rb + sp * 2 + 1) * 128 + dch * 8];
#pragma unroll
  for (int j = 0; j < 8; ++j) {
    unsigned a = bfbits(qdq(p0[j], xmax, qs));
    unsigned b = bfbits(qdq(p1[j], xmax, qs));
    Ts32[dch * 8 + j][sp] = a | (b << 16);   // keys (s0+2sp, s0+2sp+1), row dch*8+j
  }
  __syncthreads();
  const long obase = (long)(bh * 64 + blk) * 1024;   // u64 units per tile
#pragma unroll
  for (int uu = 0; uu < 2; ++uu) {
    int u_ = uu * 256 + tid;                 // 0..511: (half,hi,d)
    int half = u_ >> 8, hi = (u_ >> 7) & 1, d = u_ & 127;
    u64 qlo = *(const u64*)&Ts32[d][2 * (half * 4 + hi)];
    u64 qhi = *(const u64*)&Ts32[d][2 * (half * 4 + hi + 2)];
    vdt2[obase + u_ * 2    ] = qlo;
    vdt2[obase + u_ * 2 + 1] = qhi;
  }
}

// elementwise quantize+dequant k -> bf16 natural layout (+ inline kmax reduce)
__global__ __launch_bounds__(256) void quantize_k_kernel(
    const float* __restrict__ kr, const float* __restrict__ kpart,
    const float* __restrict__ qjl, __bf16* __restrict__ out)
{
  __shared__ float sm[4];
  const int tid = threadIdx.x;
  float m = 0.f;
  for (int i = tid; i < 2048; i += 256) m = fmaxf(m, kpart[i]);
#pragma unroll
  for (int msk = 1; msk <= 32; msk <<= 1) m = fmaxf(m, __shfl_xor(m, msk, 64));
  if ((tid & 63) == 0) sm[tid >> 6] = m;
  __syncthreads();
  const float xmax = fmaxf(fmaxf(sm[0], sm[1]), fmaxf(sm[2], sm[3])) + 1e-8f;
  const float qs = qjl[0];

  long i = ((long)blockIdx.x * 256 + tid) * 4;
  f32x4 x = *(const f32x4*)&kr[i];
  bf16x4 ov;
#pragma unroll
  for (int j = 0; j < 4; ++j) ov[j] = (__bf16)qdq(x[j], xmax, qs);
  *(bf16x4*)&out[i] = ov;
}

// ---------------------------------------------------------------------------
// attn2: key-split flash attention. grid 1024 = {kh} x {qt} x {head};
// 4 blocks/CU (32.8KB LDS, <=128 VGPR), per-tile double-buffered DMA
// pipeline. Writes unnormalized acc (kh=0 -> pA, kh=1 -> pB) + lsum partials.
// ---------------------------------------------------------------------------
__global__ __launch_bounds__(256, 4) void attn2(
    const __bf16* __restrict__ qb, const __bf16* __restrict__ kd,
    const u64* __restrict__ vdt2, const float* __restrict__ qn,
    const float* __restrict__ kpart, const float* __restrict__ qjl,
    float* __restrict__ pA, float* __restrict__ pB,
    float* __restrict__ lsumP)
{
  __shared__ __attribute__((aligned(16))) __bf16 Ks[2][32 * DH]; // 16KB
  __shared__ __attribute__((aligned(16))) u64   Vt[2][1024];     // 16KB
  __shared__ float sm[4];

  const int tid = threadIdx.x, wave = tid >> 6, lane = tid & 63;
  const int r31 = lane & 31, hi = lane >> 5;
  const int bid = blockIdx.x;
  const int kh = bid >> 9, rem = bid & 511;
  const int head = rem & 31, qt = rem >> 5;
  const long hrow = (long)head * SLEN;
  const int qrow0 = qt * 128 + wave * 32;

  // block-local reduce of kpart (identical result to a global reduce)
  float km = 0.f;
  for (int i = tid; i < 2048; i += 256) km = fmaxf(km, kpart[i]);
#pragma unroll
  for (int m = 1; m <= 32; m <<= 1) km = fmaxf(km, __shfl_xor(km, m, 64));
  if (lane == 0) sm[wave] = km;
  __syncthreads();
  const float xmax = fmaxf(fmaxf(sm[0], sm[1]), fmaxf(sm[2], sm[3])) + 1e-8f;
  const float Bk = 11.313708499f * ((3.5f + qjl[0] * xmax) * xmax / 3.5f) * 1.02f * 0.5f;

  // Q fragments, B-layout of 32x32x16 (pre-scaled by log2e/sqrt(128))
  bf16x8 qf[8];
#pragma unroll
  for (int t = 0; t < 8; ++t)
    qf[t] = *(const bf16x8*)&qb[(hrow + qrow0 + r31) * DH + t * 16 + hi * 8];
  const float mqneg = -(qn[hrow + qrow0 + r31] * Bk);   // log2-domain bound

  // Ks LDS read byte-offsets (tile-invariant): chunk (2t+hi) XOR (row&7)
  int koff[8];
#pragma unroll
  for (int t = 0; t < 8; ++t)
    koff[t] = r31 * 256 + (((2 * t + hi) ^ (r31 & 7)) << 4);

  // V LDS read base, u64 units: 16B unit (half,hi,dt,r31) lives at u64 index
  // 2*((2*half+hi)*128 + dt*32 + r31) = half*512 + hi*256 + dt*64 + 2*r31
  const int vbse = hi * 256 + 2 * r31;

  // K DMA source (swizzle-compensated, kh-half folded) / dest
  const __bf16* ksrc[2]; int kds[2];
#pragma unroll
  for (int u = 0; u < 2; ++u) {
    int c = (wave * 2 + u) * 64 + lane;
    int row = c >> 4, ch = (c & 15) ^ (row & 7);
    ksrc[u] = kd + (hrow + kh * 1024 + row) * DH + ch * 8;
    kds[u] = (wave * 2 + u) * 512;
  }
  // V DMA source: linear copy of the per-tile 8KB block (kh-half folded)
  const char* vbase = (const char*)(vdt2 + ((long)head * 64 + kh * 32) * 1024)
                      + (long)(wave * 2 * 64 + lane) * 16;

  // stage block-local tile T into buffer B: 4 DMAs/thread
  auto STAGE = [&](int B, int T) {
    const long ko = (long)T * 32 * DH;
    const long vo = (long)T * 8192;
    lds_dma16(ksrc[0] + ko, &Ks[B][kds[0]]);
    lds_dma16(ksrc[1] + ko, &Ks[B][kds[1]]);
    lds_dma16(vbase + vo,        &Vt[B][(wave * 2 + 0) * 128]);
    lds_dma16(vbase + vo + 1024, &Vt[B][(wave * 2 + 1) * 128]);
  };

  STAGE(0, 0);

  f32x16 acc[4];
#pragma unroll
  for (int dt = 0; dt < 4; ++dt) acc[dt] = zero16();
  float ls0 = 0.f, ls1 = 0.f, ls2 = 0.f, ls3 = 0.f;

#pragma unroll 2
  for (int t = 0; t < 32; ++t) {
    const int B = t & 1;
    asm volatile("s_waitcnt vmcnt(0)" ::: "memory");   // tile t landed
    __builtin_amdgcn_s_barrier();                      // all waves done with buf B
    asm volatile("" ::: "memory");
    if (t < 31) STAGE(B ^ 1, t + 1);                   // flight = this compute phase

    // S^T = K Q^T: single 8-MFMA chain, s starts at -Mq
    f32x16 s;
#pragma unroll
    for (int r = 0; r < 16; ++r) s[r] = mqneg;
    const char* kb = (const char*)&Ks[B][0];
    __builtin_amdgcn_s_setprio(1);
#pragma unroll
    for (int tt = 0; tt < 8; ++tt) {
      bf16x8 ka = *(const bf16x8*)(kb + koff[tt]);
      s = mfma_bf16_32x32x16(ka, qf[tt], s);
    }
    __builtin_amdgcn_s_setprio(0);

    // softmax numerator, P in registers
    float p[16];
#pragma unroll
    for (int r = 0; r < 16; ++r) p[r] = __builtin_amdgcn_exp2f(s[r]);
#pragma unroll
    for (int r = 0; r < 16; r += 4) {
      ls0 += p[r]; ls1 += p[r + 1]; ls2 += p[r + 2]; ls3 += p[r + 3];
    }
    bf16x8 pa, pb;
#pragma unroll
    for (int jj = 0; jj < 8; ++jj) { pa[jj] = (__bf16)p[jj]; pb[jj] = (__bf16)p[8 + jj]; }

    // PV: O[q][d] += P V  (x16, B-fragments from permuted V tile)
    const u64* vb = &Vt[B][vbse];
    __builtin_amdgcn_s_setprio(1);
#pragma unroll
    for (int dt = 0; dt < 4; ++dt)
      acc[dt] = mfma_bf16_32x32x16(pa, *(const bf16x8*)(vb + dt * 64), acc[dt]);
#pragma unroll
    for (int dt = 0; dt < 4; ++dt)
      acc[dt] = mfma_bf16_32x32x16(pb, *(const bf16x8*)(vb + 512 + dt * 64), acc[dt]);
    __builtin_amdgcn_s_setprio(0);
  }

  // partial lsum: combine hi-halves -> per-q-row value
  float lsum = (ls0 + ls1) + (ls2 + ls3);
  lsum += __shfl_xor(lsum, 32, 64);
  if (hi == 0) lsumP[(long)kh * 65536 + hrow + qrow0 + r31] = lsum;

  float* dst = kh ? pB : pA;
#pragma unroll
  for (int dt = 0; dt < 4; ++dt)
#pragma unroll
    for (int r = 0; r < 16; ++r) {
      int qr = (r & 3) + 8 * (r >> 2) + 4 * hi;
      dst[(hrow + qrow0 + qr) * DH + dt * 32 + r31] = acc[dt][r];
    }
}

// ---------------------------------------------------------------------------
extern "C" void kernel_launch(void* const* d_in, const int* in_sizes, int n_in,
                              void* d_out, int out_size, void* d_ws, size_t ws_size,
                              hipStream_t stream)
{
  const float* q   = (const float*)d_in[0];
  const float* k   = (const float*)d_in[1];
  const float* v   = (const float*)d_in[2];
  const float* R   = (const float*)d_in[3];
  const float* qjl = (const float*)d_in[4];

  char* ws = (char*)d_ws;
  float* kpart = (float*)ws;                      // [2048]
  float* vpart = (float*)(ws + 8192);             // [2048]
  _Float16* Bhi  = (_Float16*)(ws + 32768);       // R row-major f16 hi (32KB)
  _Float16* Blo  = (_Float16*)(ws + 65536);
  _Float16* BhiT = (_Float16*)(ws + 98304);       // R^T f16 hi
  _Float16* BloT = (_Float16*)(ws + 131072);
  float* qn = (float*)(ws + 163840);              // [65536] (256KB)
  char* base = ws + 425984;
  __bf16* qb   = (__bf16*)base;                                 // 16 MiB
  float*  kr   = (float*)(base + (16u << 20));                  // 32 MiB
  float*  vr   = (float*)(base + (48u << 20));                  // 32 MiB
  u64*    vdt2 = (u64*)(base + (80u << 20));                    // 16 MiB
  __bf16* kd   = (__bf16*)vr;   // vr lower 16MB, reused after quantize_vt read vr
  float* lsumP = (float*)(base + (64u << 20));    // vr upper half: [2][65536]
  float* orot  = kr;            // partial A (kh=0), reuse kr after quantize_k
  float* pB    = (float*)d_out; // partial B (kh=1): d_out as scratch

  dim3 b256(256);
  prep_R<<<64, b256, 0, stream>>>(R, Bhi, Blo, BhiT, BloT);
  rot_kv_kernel<<<1024, b256, 0, stream>>>(k, v, BhiT, BloT, kr, vr, kpart, vpart);
  rot_q_kernel<<<512, b256, 0, stream>>>(q, BhiT, BloT, qb, qn);
  quantize_vt_kernel<<<2048, b256, 0, stream>>>(vr, vpart, qjl, vdt2);
  quantize_k_kernel<<<8192, b256, 0, stream>>>(kr, kpart, qjl, kd);
  attn2<<<1024, b256, 0, stream>>>(qb, kd, vdt2, qn, kpart, qjl, orot, pB, lsumP);
  rot_oc_kernel<<<512, b256, 0, stream>>>(orot, pB, lsumP, Bhi, (float*)d_out);
}